// Round 14
// baseline (121.090 us; speedup 1.0000x reference)
//
#include <hip/hip_runtime.h>
#include <cstdint>
#include <cstddef>

// ---------------------------------------------------------------------------
// Gated attention (AlphaFold-style), MI355X / gfx950.
// B=32, Q=K=512, A=256, H=8, C=32, O=256.  All inputs fp32, output fp32.
// R14: attn k-tile doubled KT=32 -> 64. Bias tile [256 q][64 k] fp32 (64KB,
//   SINGLE buffer): each 2KB bbias row now visited 8x at 256B contiguous
//   (was 16x at 128B) -> ~half the DRAM row activations on the 268MB stream.
//   Single-buffer is safe: each wave overwrites ONLY ITS OWN rows after
//   lgkmcnt(0)-fencing its reads (per-wave-own-rows, no cross-wave hazard).
//   DMA(t+1) issued pre-compute (~1400cy cover); vmcnt(8) leaves nbias(t+1)
//   in flight. 16 tokens; same verified MFMA/swizzle structure (key=row&15).
//   Keeps R13's setprio + named qf0/qf1.
// ---------------------------------------------------------------------------

typedef __attribute__((ext_vector_type(8))) short short8;   // 8 x bf16 (raw bits)
typedef __attribute__((ext_vector_type(4))) float f32x4;
typedef __attribute__((ext_vector_type(4))) unsigned int u32x4;
typedef __attribute__((ext_vector_type(2))) unsigned int u32x2;

#define DEVFN static __device__ __forceinline__
#define L2E 1.4426950408889634f

DEVFN float b2f(unsigned int bits16) {        // bf16 bits -> fp32
  return __builtin_bit_cast(float, bits16 << 16);
}
DEVFN unsigned int pack2(float a, float b) {  // two bf16 (RNE) in one dword
  unsigned int r;
  asm("v_cvt_pk_bf16_f32 %0, %1, %2" : "=v"(r) : "v"(a), "v"(b));
  return r;
}
DEVFN f32x4 mfma16(short8 a, short8 b, f32x4 c) {
  return __builtin_amdgcn_mfma_f32_16x16x32_bf16(a, b, c, 0, 0, 0);
}
// aux=2 -> gfx950 CPol NT bit: non-temporal, do not pollute L2/L3.
#define GLOAD_LDS16_NT(gp, lp)                                     \
  __builtin_amdgcn_global_load_lds(                                \
      (const __attribute__((address_space(1))) void*)(gp),         \
      (__attribute__((address_space(3))) void*)(lp), 16, 0, 2)
// MFMA 16x16x32 layouts (gfx950, per verified guide):
//  A: row = lane&15,           k = 8*(lane>>4)+j   (j=0..7)
//  B: col = lane&15,           k = 8*(lane>>4)+j
//  D: col = lane&15,           row = 4*(lane>>4)+r (r=0..3)

// ---------------------------------------------------------------------------
// Kernel 0: transpose 5 weight matrices [256][256] fp32 -> bf16 W^T [n][a]
// ---------------------------------------------------------------------------
__global__ __launch_bounds__(256) void wtrans_kernel(
    const float* __restrict__ qw, const float* __restrict__ kw,
    const float* __restrict__ vw, const float* __restrict__ gw,
    const float* __restrict__ ow,
    unsigned short* __restrict__ wtq, unsigned short* __restrict__ wtk,
    unsigned short* __restrict__ wtv, unsigned short* __restrict__ wtg,
    unsigned short* __restrict__ wt3)
{
  const int matid = blockIdx.x >> 4;
  const int tile  = blockIdx.x & 15;
  const float* src = (matid == 0) ? qw : (matid == 1) ? kw : (matid == 2) ? vw
                   : (matid == 3) ? gw : ow;
  unsigned short* dst = (matid == 0) ? wtq : (matid == 1) ? wtk : (matid == 2) ? wtv
                      : (matid == 3) ? wtg : wt3;
  const int tr = (tile >> 2) * 64, tc = (tile & 3) * 64;
  __shared__ unsigned short T[64 * 72];
  const int t = threadIdx.x;
  {
    const int row = t >> 2, cb = (t & 3) * 16;
#pragma unroll
    for (int ii = 0; ii < 4; ++ii) {
      f32x4 v = *(const f32x4*)&src[(size_t)(tr + row) * 256 + tc + cb + ii * 4];
      u32x2 p; p.x = pack2(v.x, v.y); p.y = pack2(v.z, v.w);
      *(u32x2*)&T[row * 72 + cb + ii * 4] = p;
    }
  }
  __syncthreads();
  {
    const int c0 = t >> 2, rb = (t & 3) * 16;
    unsigned short vals[16];
#pragma unroll
    for (int m = 0; m < 16; ++m) vals[m] = T[(rb + m) * 72 + c0];
    u32x4 s0, s1;
    s0.x = (unsigned)vals[0]  | ((unsigned)vals[1]  << 16);
    s0.y = (unsigned)vals[2]  | ((unsigned)vals[3]  << 16);
    s0.z = (unsigned)vals[4]  | ((unsigned)vals[5]  << 16);
    s0.w = (unsigned)vals[6]  | ((unsigned)vals[7]  << 16);
    s1.x = (unsigned)vals[8]  | ((unsigned)vals[9]  << 16);
    s1.y = (unsigned)vals[10] | ((unsigned)vals[11] << 16);
    s1.z = (unsigned)vals[12] | ((unsigned)vals[13] << 16);
    s1.w = (unsigned)vals[14] | ((unsigned)vals[15] << 16);
    unsigned short* dp = &dst[(size_t)(tc + c0) * 256 + tr + rb];
    *(u32x4*)dp = s0;
    *(u32x4*)(dp + 8) = s1;
  }
}

// ---------------------------------------------------------------------------
// Kernel 1: projections. blocks 0..255: q_data -> qp + gate.
//           blocks 256..511: m_data -> kp + vp.  All outputs [B,H,S,C].
// qp scaled by keyscale*log2e.
// ---------------------------------------------------------------------------
__global__ __launch_bounds__(512, 4) void proj_kernel(
    const float* __restrict__ q_data, const float* __restrict__ m_data,
    const unsigned short* __restrict__ wtq, const unsigned short* __restrict__ wtk,
    const unsigned short* __restrict__ wtv, const unsigned short* __restrict__ wtg,
    const float* __restrict__ gating_b,
    unsigned short* __restrict__ qp, unsigned short* __restrict__ kp,
    unsigned short* __restrict__ vp, unsigned short* __restrict__ gate)
{
  const int bid = blockIdx.x;
  const bool mside = bid >= 256;
  const int r0 = (mside ? bid - 256 : bid) * 64;
  const float* inp = mside ? m_data : q_data;
  __shared__ unsigned short Alds[64 * 264];       // 64 rows x 256 a, pad 264
  __shared__ unsigned short Wlds[2][256 * 40];    // dbuf: 256 n x 32 a-slice
  const int t = threadIdx.x;
  const int lane = t & 63, wave = t >> 6;
  const int l15 = lane & 15, g = lane >> 4;
  const int stripe = wave & 3, nhalf = wave >> 2;

  { // stage A tile as bf16: 512 threads x 32 floats
    const int row = t >> 3, cb = (t & 7) * 32;
    const float* ip = &inp[(size_t)(r0 + row) * 256 + cb];
#pragma unroll
    for (int i = 0; i < 4; ++i) {
      f32x4 a0 = *(const f32x4*)&ip[i * 8];
      f32x4 a1 = *(const f32x4*)&ip[i * 8 + 4];
      u32x4 pk;
      pk.x = pack2(a0.x, a0.y); pk.y = pack2(a0.z, a0.w);
      pk.z = pack2(a1.x, a1.y); pk.w = pack2(a1.z, a1.w);
      *(u32x4*)&Alds[row * 264 + cb + i * 8] = pk;
    }
  }

  const unsigned short* wt0 = mside ? wtk : wtq;
  const unsigned short* wt1 = mside ? wtv : wtg;
  const int wrow = t & 255, whalf = t >> 8;       // W staging: 2 threads/row

  { // prologue: W slice 0 -> buf 0
    const u32x4* wsrc = (const u32x4*)&wt0[(size_t)wrow * 256 + whalf * 16];
    u32x4 a = wsrc[0], b = wsrc[1];
    *(u32x4*)&Wlds[0][wrow * 40 + whalf * 16 + 0] = a;
    *(u32x4*)&Wlds[0][wrow * 40 + whalf * 16 + 8] = b;
  }

  f32x4 acc[8];
#pragma unroll
  for (int j = 0; j < 8; ++j) acc[j] = f32x4{0.f, 0.f, 0.f, 0.f};

  const int arow = (stripe * 16 + l15) * 264 + 8 * g;
  const int grow = r0 + stripe * 16 + l15;        // B-col -> data row (b*512+q)
  const int ob = grow >> 9, oq = grow & 511;

#pragma unroll
  for (int s = 0; s < 16; ++s) {                  // s = oi*8 + ks
    const int p = s & 1;
    __syncthreads();                               // buf p ready; buf p^1 free
    u32x4 nw0, nw1;
    if (s < 15) {                                  // issue next-slice W load
      const unsigned short* wt = (s + 1 < 8) ? wt0 : wt1;
      const u32x4* wsrc =
          (const u32x4*)&wt[(size_t)wrow * 256 + ((s + 1) & 7) * 32 + whalf * 16];
      nw0 = wsrc[0]; nw1 = wsrc[1];
    }
    const int ks = s & 7;
    short8 bf = __builtin_bit_cast(short8, *(const u32x4*)&Alds[arow + ks * 32]);
#pragma unroll
    for (int j = 0; j < 8; ++j) {
      short8 wf = __builtin_bit_cast(short8,
          *(const u32x4*)&Wlds[p][((nhalf * 8 + j) * 16 + l15) * 40 + 8 * g]);
      acc[j] = mfma16(wf, bf, acc[j]);             // D: row=n(4g+r), col=q(l15)
    }
    if (s < 15) {
      *(u32x4*)&Wlds[p ^ 1][wrow * 40 + whalf * 16 + 0] = nw0;
      *(u32x4*)&Wlds[p ^ 1][wrow * 40 + whalf * 16 + 8] = nw1;
    }
    if (s == 7 || s == 15) {                       // epilogue per oi
      const int oi = s >> 3;
      const float QS = 0.17677669529663687f * 1.4426950408889634f;
#pragma unroll
      for (int j = 0; j < 8; ++j) {
        const int n0 = (nhalf * 8 + j) * 16 + 4 * g;  // 4 consecutive n / lane
        const int h = n0 >> 5, c0 = n0 & 31;
        const size_t idx = ((size_t)(ob * 8 + h) * 512 + oq) * 32 + c0;
        f32x4 v = acc[j];
        if (!mside) {
          if (oi == 0) {
            u32x2 st;
            st.x = pack2(v.x * QS, v.y * QS);
            st.y = pack2(v.z * QS, v.w * QS);
            *(u32x2*)&qp[idx] = st;
          } else {
            f32x4 gb = *(const f32x4*)&gating_b[n0];
            f32x4 gv;
            gv.x = 1.0f / (1.0f + exp2f(-(v.x + gb.x) * L2E));
            gv.y = 1.0f / (1.0f + exp2f(-(v.y + gb.y) * L2E));
            gv.z = 1.0f / (1.0f + exp2f(-(v.z + gb.z) * L2E));
            gv.w = 1.0f / (1.0f + exp2f(-(v.w + gb.w) * L2E));
            u32x2 st;
            st.x = pack2(gv.x, gv.y); st.y = pack2(gv.z, gv.w);
            *(u32x2*)&gate[idx] = st;              // gate stored bf16
          }
        } else {
          u32x2 st;
          st.x = pack2(v.x, v.y); st.y = pack2(v.z, v.w);
          if (oi == 0) *(u32x2*)&kp[idx] = st;
          else         *(u32x2*)&vp[idx] = st;
        }
        acc[j] = f32x4{0.f, 0.f, 0.f, 0.f};
      }
    }
  }
}

// ---------------------------------------------------------------------------
// Kernel 2: fused attention. Grid 256 = (b,h); 1 block/CU; 8 waves.
// Two q-passes (256 rows each, wave owns 32 rows/pass) over ONE K/V staging.
// Token t = pass*8 + kt8 (16 tokens, KT=64). Bias tile Bt [256 q][64 k] fp32
// (64KB, SINGLE buffer): wave w owns rows w*32..w*32+31; per token it fences
// its rows into regs (lgkmcnt(0)) then DMAs window t+1 into the SAME rows
// (own-rows-only -> no cross-wave hazard). 8 DMA chunks/wave/window, each
// 4 rows x 256B contiguous source. XOR swizzle key = row&15 both sides.
// Order: ds_reads -> fence -> DMA(t+1) -> nbias(t+1) -> setprio compute ->
// vmcnt(8) (drains DMA, leaves nbias). 8 S-MFMAs + 4 PV-MFMAs per token.
// ---------------------------------------------------------------------------
__global__ __launch_bounds__(512, 2) void attn_kernel(
    const unsigned short* __restrict__ qp, const unsigned short* __restrict__ kp,
    const unsigned short* __restrict__ vp,
    const float* __restrict__ bias, const float* __restrict__ nbias,
    const float* __restrict__ bbias,
    unsigned short* __restrict__ wa)
{
  const int bid = blockIdx.x;               // = b*8 + h
  const int h = bid & 7;                    // same-h blocks share an XCD -> nbias L2-hot
  const int b = bid >> 3;
  const int bh = bid;
  const int t = threadIdx.x;
  const int lane = t & 63, wave = t >> 6;
  const int l15 = lane & 15, g = lane >> 4;

  __shared__ unsigned short Klds[512 * 32];  // [k][c] unpadded (contiguous reads)
  __shared__ unsigned short Vt[32 * 520];    // V^T [c][k], pad 520 (2-way)
  __shared__ float Bt[256 * 64];             // bias tile [256 q][64 k], 64KB
  __shared__ float Bk[512];                  // bias row * log2e

  // bbias DMA: chunk c (0..7) covers tile rows wave*32 + c*4 + qc4
  // (qc4 = lane>>4); sl16 = lane&15 = 16B slot; source slot pre-swizzled
  // with key (c*4+qc4)&15 (= row&15; involution matches read-side XOR).
  const float* bbb_bh = bbias + (size_t)bh * 262144;
  const int qc4 = lane >> 4, sl16 = lane & 15;
  const float* wbase = bbb_bh + (size_t)(wave * 32 + qc4) * 512;

  // prologue: DMA window 0 (pass 0, kt8 0)
#pragma unroll
  for (int c = 0; c < 8; ++c)
    GLOAD_LDS16_NT(wbase + (size_t)(c * 4) * 512 + ((sl16 ^ ((c * 4 + qc4) & 15)) << 2),
                   &Bt[(wave * 32 + c * 4) * 64]);

  { // stage K rows + transposed V (512 threads, one k-row each)
    const int row = t;
    const u32x4* ks = (const u32x4*)&kp[((size_t)bh * 512 + row) * 32];
    u32x4 k0 = ks[0], k1 = ks[1], k2 = ks[2], k3 = ks[3];
    *(u32x4*)&Klds[row * 32 + 0]  = k0;
    *(u32x4*)&Klds[row * 32 + 8]  = k1;
    *(u32x4*)&Klds[row * 32 + 16] = k2;
    *(u32x4*)&Klds[row * 32 + 24] = k3;
    const u32x4* vs = (const u32x4*)&vp[((size_t)bh * 512 + row) * 32];
#pragma unroll
    for (int cc = 0; cc < 4; ++cc) {
      u32x4 vv = vs[cc];
      unsigned int dw0 = vv.x, dw1 = vv.y, dw2 = vv.z, dw3 = vv.w;
      const int c = cc * 8;
      Vt[(c + 0) * 520 + row] = (unsigned short)(dw0 & 0xffff);
      Vt[(c + 1) * 520 + row] = (unsigned short)(dw0 >> 16);
      Vt[(c + 2) * 520 + row] = (unsigned short)(dw1 & 0xffff);
      Vt[(c + 3) * 520 + row] = (unsigned short)(dw1 >> 16);
      Vt[(c + 4) * 520 + row] = (unsigned short)(dw2 & 0xffff);
      Vt[(c + 5) * 520 + row] = (unsigned short)(dw2 >> 16);
      Vt[(c + 6) * 520 + row] = (unsigned short)(dw3 & 0xffff);
      Vt[(c + 7) * 520 + row] = (unsigned short)(dw3 >> 16);
    }
    if (t < 128) {                           // stage bias row, pre-scaled
      f32x4 bv = *(const f32x4*)&bias[(size_t)b * 512 + t * 4];
      bv.x *= L2E; bv.y *= L2E; bv.z *= L2E; bv.w *= L2E;
      *(f32x4*)&Bk[t * 4] = bv;
    }
  }

  const int pib = ((g & 1) << 4) | ((g >> 1) << 3);  // pi = [0,16,8,24]
  const bool godd = (g & 1) != 0;
  // tile read rows (qt0 / qt1) and swizzled per-kk slot offsets (floats)
  const int tr0 = (wave * 32 + l15) * 64;            // qt0 row base
  const int tr1 = tr0 + 16 * 64;                     // qt1 rows
  // slot for (kk,g): (kk*4+g) ^ l15, key=row&15=l15

  // nbias Cn for token 0 (8 frags: [qt][kk], unrolled-index only)
  f32x4 Cn[2][4];
  {
    const float* nn0 = nbias + (size_t)h * 262144
                     + (size_t)(wave * 32 + l15) * 512 + 4 * g;
#pragma unroll
    for (int qt = 0; qt < 2; ++qt)
#pragma unroll
      for (int kk = 0; kk < 4; ++kk)
        Cn[qt][kk] = *(const f32x4*)(nn0 + (size_t)qt * 16 * 512 + kk * 16);
  }

  short8 qf0, qf1;
  f32x4 acc[2][2];
  float l_part[2] = {0.f, 0.f};

  asm volatile("s_waitcnt vmcnt(0)" ::: "memory");  // window 0 + regs done
  __syncthreads();   // K/V/Bk visible to all waves

  for (int tok = 0; tok < 16; ++tok) {
    const int pass = tok >> 3, kt8 = tok & 7;
    const int k0 = kt8 * 64;

    if (kt8 == 0) {  // pass start: load Q fragments (named regs), reset acc
      const int qbase = pass * 256 + wave * 32;
      qf0 = __builtin_bit_cast(short8,
          *(const u32x4*)&qp[((size_t)bh * 512 + qbase + l15) * 32 + 8 * g]);
      qf1 = __builtin_bit_cast(short8,
          *(const u32x4*)&qp[((size_t)bh * 512 + qbase + 16 + l15) * 32 + 8 * g]);
#pragma unroll
      for (int ct = 0; ct < 2; ++ct)
#pragma unroll
        for (int qt = 0; qt < 2; ++qt) acc[ct][qt] = f32x4{0.f, 0.f, 0.f, 0.f};
      l_part[0] = 0.f; l_part[1] = 0.f;
    }

    // LDS reads for this token: K (4), V (4), Bk (4), bias tile (8)
    short8 kf[4], vf[2][2];
    f32x4 bks[4], bb0[4], bb1[4];
#pragma unroll
    for (int kk = 0; kk < 4; ++kk) {
      kf[kk] = __builtin_bit_cast(short8,
          *(const u32x4*)&Klds[(k0 + kk * 16 + l15) * 32 + 8 * g]);
      bks[kk] = *(const f32x4*)&Bk[k0 + kk * 16 + 4 * g];
      const int slot = ((kk * 4 + g) ^ l15) << 2;
      bb0[kk] = *(const f32x4*)&Bt[tr0 + slot];
      bb1[kk] = *(const f32x4*)&Bt[tr1 + slot];
    }
#pragma unroll
    for (int ks = 0; ks < 2; ++ks) {
      vf[0][ks] = __builtin_bit_cast(short8,
          *(const u32x4*)&Vt[l15 * 520 + k0 + ks * 32 + pib]);
      vf[1][ks] = __builtin_bit_cast(short8,
          *(const u32x4*)&Vt[(16 + l15) * 520 + k0 + ks * 32 + pib]);
    }
    // tile regs must be materialized before the same-rows DMA below
    asm volatile("s_waitcnt lgkmcnt(0)" ::: "memory");
    __builtin_amdgcn_sched_barrier(0);

    // DMA window tok+1 into the SAME rows (just consumed), then nbias(t+1)
    if (tok < 15) {
      const int ft = tok + 1;
      const float* ws = wbase + (size_t)(ft >> 3) * 131072 + (ft & 7) * 64;
#pragma unroll
      for (int c = 0; c < 8; ++c)
        GLOAD_LDS16_NT(ws + (size_t)(c * 4) * 512 + ((sl16 ^ ((c * 4 + qc4) & 15)) << 2),
                       &Bt[(wave * 32 + c * 4) * 64]);
    }
    f32x4 Nn[2][4];
    if (tok < 15) {
      const int nt = tok + 1;
      const float* nn0 = nbias + (size_t)h * 262144
          + (size_t)((nt >> 3) * 256 + wave * 32 + l15) * 512 + (nt & 7) * 64 + 4 * g;
#pragma unroll
      for (int qt = 0; qt < 2; ++qt)
#pragma unroll
        for (int kk = 0; kk < 4; ++kk)
          Nn[qt][kk] = *(const f32x4*)(nn0 + (size_t)qt * 16 * 512 + kk * 16);
    }

    // compute both q-tiles (T5 setprio)
    __builtin_amdgcn_s_setprio(1);
#pragma unroll
    for (int qt = 0; qt < 2; ++qt) {
      short8 qf = qt ? qf1 : qf0;
      f32x4 pr[4];
#pragma unroll
      for (int kk = 0; kk < 4; ++kk) {
        f32x4 bb = qt ? bb1[kk] : bb0[kk];
        f32x4 c = bb * L2E + (Cn[qt][kk] * L2E + bks[kk]);
        f32x4 s = mfma16(kf[kk], qf, c);     // S^T: row k=k0+kk*16+4g+r
        f32x4 pe;
        pe.x = exp2f(s.x); pe.y = exp2f(s.y);
        pe.z = exp2f(s.z); pe.w = exp2f(s.w);
        l_part[qt] += (pe.x + pe.y) + (pe.z + pe.w);
        pr[kk] = pe;
      }
#pragma unroll
      for (int ks = 0; ks < 2; ++ks) {
        f32x4 p0 = pr[2 * ks], p1 = pr[2 * ks + 1];
        unsigned int d0 = pack2(p0.x, p0.y), d1 = pack2(p0.z, p0.w);
        unsigned int e0 = pack2(p1.x, p1.y), e1 = pack2(p1.z, p1.w);
        unsigned int pd0 = __shfl_xor(d0, 16, 64), pd1 = __shfl_xor(d1, 16, 64);
        unsigned int pe0 = __shfl_xor(e0, 16, 64), pe1 = __shfl_xor(e1, 16, 64);
        u32x4 pfu;
        pfu.x = godd ? pe0 : d0;
        pfu.y = godd ? pe1 : d1;
        pfu.z = godd ? e0 : pd0;
        pfu.w = godd ? e1 : pd1;
        short8 pf = __builtin_bit_cast(short8, pfu);
        acc[0][qt] = mfma16(vf[0][ks], pf, acc[0][qt]);   // wa^T: row c, col q
        acc[1][qt] = mfma16(vf[1][ks], pf, acc[1][qt]);
      }
    }
    __builtin_amdgcn_s_setprio(0);

#pragma unroll
    for (int qt = 0; qt < 2; ++qt)
#pragma unroll
      for (int kk = 0; kk < 4; ++kk)
        if (tok < 15) Cn[qt][kk] = Nn[qt][kk];

    // counted wait: drains DMA(t+1) (oldest 8), leaves nbias(t+1) in flight
    if (tok < 15) asm volatile("s_waitcnt vmcnt(8)" ::: "memory");

    if (kt8 == 7) {  // pass epilogue
      const int qbase = pass * 256 + wave * 32;
      unsigned short* wab = wa + (size_t)bh * 512 * 32;
#pragma unroll
      for (int qt = 0; qt < 2; ++qt) {
        float l = l_part[qt];
        l += __shfl_xor(l, 16, 64);
        l += __shfl_xor(l, 32, 64);
        const float rl = 1.0f / l;
        const int q = qbase + qt * 16 + l15;
#pragma unroll
        for (int ct = 0; ct < 2; ++ct) {
          f32x4 v = acc[ct][qt];
          u32x2 st;
          st.x = pack2(v.x * rl, v.y * rl);
          st.y = pack2(v.z * rl, v.w * rl);
          *(u32x2*)&wab[q * 32 + ct * 16 + 4 * g] = st;
        }
      }
    }
  }
}

// ---------------------------------------------------------------------------
// Kernel 3: out[b,q,o] = sum_hc wa*gate * W3[hc][o] + output_b[o]
// 32 rows/block (grid 512 -> 2 blocks/CU), n-split across wave pairs;
// gate read bf16; W3 dbuf; act prefetched; cvt_pk packs.
// ---------------------------------------------------------------------------
__global__ __launch_bounds__(256, 2) void outp_kernel(
    const unsigned short* __restrict__ wa, const unsigned short* __restrict__ gate,
    const unsigned short* __restrict__ wt3, const float* __restrict__ out_b,
    float* __restrict__ out)
{
  const int r0 = blockIdx.x * 32;
  const int t = threadIdx.x;
  const int lane = t & 63, wave = t >> 6;
  const int l15 = lane & 15, g = lane >> 4;
  const int stripe = wave & 1, half = wave >> 1;
  __shared__ unsigned short Wlds[2][256 * 40];

  const int grow = r0 + stripe * 16 + l15;   // B-col -> data row (b*512+q)
  const int b = grow >> 9, q = grow & 511;

  { // prologue: W3 slice 0 -> buf 0 (256 threads, one n-row each)
    const u32x4* wsrc = (const u32x4*)&wt3[(size_t)t * 256];
    u32x4 a = wsrc[0], bb = wsrc[1], c = wsrc[2], d = wsrc[3];
    *(u32x4*)&Wlds[0][t * 40 + 0]  = a;
    *(u32x4*)&Wlds[0][t * 40 + 8]  = bb;
    *(u32x4*)&Wlds[0][t * 40 + 16] = c;
    *(u32x4*)&Wlds[0][t * 40 + 24] = d;
  }
  // prologue: activation slice 0 (h = 0)
  size_t aidx = ((size_t)(b * 8 + 0) * 512 + q) * 32 + 8 * g;
  u32x4 cwv = *(const u32x4*)&wa[aidx];
  u32x4 cgv = *(const u32x4*)&gate[aidx];

  f32x4 acc[8];
#pragma unroll
  for (int j = 0; j < 8; ++j) acc[j] = f32x4{0.f, 0.f, 0.f, 0.f};

#pragma unroll
  for (int s = 0; s < 8; ++s) {              // slice s: h = s, c = 8g..8g+7
    const int p = s & 1;
    __syncthreads();
    u32x4 nw0, nw1, nw2, nw3, nwv, ngv;
    if (s < 7) {
      const u32x4* wsrc = (const u32x4*)&wt3[(size_t)t * 256 + (s + 1) * 32];
      nw0 = wsrc[0]; nw1 = wsrc[1]; nw2 = wsrc[2]; nw3 = wsrc[3];
      const size_t na = ((size_t)(b * 8 + s + 1) * 512 + q) * 32 + 8 * g;
      nwv = *(const u32x4*)&wa[na];
      ngv = *(const u32x4*)&gate[na];
    }
    // build gated-activation B-fragment from current regs (both bf16)
    float f0 = b2f(cwv.x & 0xffff) * b2f(cgv.x & 0xffff);
    float f1 = b2f(cwv.x >> 16)    * b2f(cgv.x >> 16);
    float f2 = b2f(cwv.y & 0xffff) * b2f(cgv.y & 0xffff);
    float f3 = b2f(cwv.y >> 16)    * b2f(cgv.y >> 16);
    float f4 = b2f(cwv.z & 0xffff) * b2f(cgv.z & 0xffff);
    float f5 = b2f(cwv.z >> 16)    * b2f(cgv.z >> 16);
    float f6 = b2f(cwv.w & 0xffff) * b2f(cgv.w & 0xffff);
    float f7 = b2f(cwv.w >> 16)    * b2f(cgv.w >> 16);
    u32x4 au;
    au.x = pack2(f0, f1); au.y = pack2(f2, f3);
    au.z = pack2(f4, f5); au.w = pack2(f6, f7);
    short8 af = __builtin_bit_cast(short8, au);
#pragma unroll
    for (int j = 0; j < 8; ++j) {
      short8 wf = __builtin_bit_cast(short8,
          *(const u32x4*)&Wlds[p][((half * 8 + j) * 16 + l15) * 40 + 8 * g]);
      acc[j] = mfma16(wf, af, acc[j]);       // D: row=o(4g+r), col=q(l15)
    }
    if (s < 7) {
      *(u32x4*)&Wlds[p ^ 1][t * 40 + 0]  = nw0;
      *(u32x4*)&Wlds[p ^ 1][t * 40 + 8]  = nw1;
      *(u32x4*)&Wlds[p ^ 1][t * 40 + 16] = nw2;
      *(u32x4*)&Wlds[p ^ 1][t * 40 + 24] = nw3;
      cwv = nwv; cgv = ngv;
    }
  }
#pragma unroll
  for (int j = 0; j < 8; ++j) {
    const int o0 = (half * 8 + j) * 16 + 4 * g;  // 4 consecutive o per lane
    f32x4 ob4 = *(const f32x4*)&out_b[o0];
    f32x4 v = acc[j] + ob4;
    *(f32x4*)&out[(size_t)grow * 256 + o0] = v;
  }
}

// ---------------------------------------------------------------------------
extern "C" void kernel_launch(void* const* d_in, const int* in_sizes, int n_in,
                              void* d_out, int out_size, void* d_ws, size_t ws_size,
                              hipStream_t stream)
{
  const float* q_data   = (const float*)d_in[0];
  const float* m_data   = (const float*)d_in[1];
  const float* bias     = (const float*)d_in[2];
  const float* nbb      = (const float*)d_in[3];
  const float* bbb      = (const float*)d_in[4];
  const float* query_w  = (const float*)d_in[5];
  const float* key_w    = (const float*)d_in[6];
  const float* value_w  = (const float*)d_in[7];
  const float* gating_w = (const float*)d_in[8];
  const float* gating_b = (const float*)d_in[9];
  const float* output_w = (const float*)d_in[10];
  const float* output_b = (const float*)d_in[11];
  float* out = (float*)d_out;

  const size_t QP_B   = (size_t)32 * 8 * 512 * 32 * 2;  // 8 MiB bf16 [B,H,S,C]
  const size_t GATE_B = (size_t)32 * 8 * 512 * 32 * 2;  // 8 MiB bf16
  const size_t WT_B   = (size_t)256 * 256 * 2;

  char* ws = (char*)d_ws;
  unsigned short* qp  = (unsigned short*)(ws);
  unsigned short* kp  = (unsigned short*)(ws + QP_B);
  unsigned short* vp  = (unsigned short*)(ws + 2 * QP_B);
  unsigned short* wab = (unsigned short*)(ws + 3 * QP_B);
  unsigned short* gat = (unsigned short*)(ws + 4 * QP_B);
  unsigned short* wtq = (unsigned short*)(ws + 4 * QP_B + GATE_B);
  unsigned short* wtk = (unsigned short*)(ws + 4 * QP_B + GATE_B + WT_B);
  unsigned short* wtv = (unsigned short*)(ws + 4 * QP_B + GATE_B + 2 * WT_B);
  unsigned short* wtg = (unsigned short*)(ws + 4 * QP_B + GATE_B + 3 * WT_B);
  unsigned short* wt3 = (unsigned short*)(ws + 4 * QP_B + GATE_B + 4 * WT_B);
  const size_t need = 4 * QP_B + GATE_B + 5 * WT_B;
  if (ws_size < need) return;  // fail loudly (out stays poisoned)

  hipLaunchKernelGGL(wtrans_kernel, dim3(80), dim3(256), 0, stream,
                     query_w, key_w, value_w, gating_w, output_w,
                     wtq, wtk, wtv, wtg, wt3);
  hipLaunchKernelGGL(proj_kernel, dim3(512), dim3(512), 0, stream,
                     q_data, m_data, wtq, wtk, wtv, wtg, gating_b,
                     qp, kp, vp, gat);
  hipLaunchKernelGGL(attn_kernel, dim3(256), dim3(512), 0, stream,
                     qp, kp, vp, bias, nbb, bbb, wab);
  hipLaunchKernelGGL(outp_kernel, dim3(512), dim3(256), 0, stream,
                     wab, gat, wt3, output_b, out);
}

// Round 15
// 120.158 us; speedup vs baseline: 1.0078x; 1.0078x over previous
//
#include <hip/hip_runtime.h>
#include <cstdint>
#include <cstddef>

// ---------------------------------------------------------------------------
// Gated attention (AlphaFold-style), MI355X / gfx950.
// B=32, Q=K=512, A=256, H=8, C=32, O=256.  All inputs fp32, output fp32.
// R15 (FINAL): lock-in of R13, the session best (120.9us; R14's KT=64 was
//   null at 121.1 -> reverted). Session: 209 -> 120.9us.
//   attn: grid 256=(b,h), 1 blk/CU, 8 waves, 2 q-passes over one K/V
//   staging; bbias tile [256 q][32 k] fp32 dbuf, NT global_load_lds DMA
//   2 tokens ahead, per-wave-own-rows (no in-loop barriers), vmcnt(8)
//   counted waits, setprio around compute, named qf0/qf1 regs (rule #20).
//   Falsified for the residual attn gap: issue rate, staging, MLP depth,
//   drain ordering, NT policy, k-split, K-direct, DMA granularity.
// ---------------------------------------------------------------------------

typedef __attribute__((ext_vector_type(8))) short short8;   // 8 x bf16 (raw bits)
typedef __attribute__((ext_vector_type(4))) float f32x4;
typedef __attribute__((ext_vector_type(4))) unsigned int u32x4;
typedef __attribute__((ext_vector_type(2))) unsigned int u32x2;

#define DEVFN static __device__ __forceinline__
#define L2E 1.4426950408889634f

DEVFN float b2f(unsigned int bits16) {        // bf16 bits -> fp32
  return __builtin_bit_cast(float, bits16 << 16);
}
DEVFN unsigned int pack2(float a, float b) {  // two bf16 (RNE) in one dword
  unsigned int r;
  asm("v_cvt_pk_bf16_f32 %0, %1, %2" : "=v"(r) : "v"(a), "v"(b));
  return r;
}
DEVFN f32x4 mfma16(short8 a, short8 b, f32x4 c) {
  return __builtin_amdgcn_mfma_f32_16x16x32_bf16(a, b, c, 0, 0, 0);
}
// aux=2 -> gfx950 CPol NT bit: non-temporal, do not pollute L2/L3.
#define GLOAD_LDS16_NT(gp, lp)                                     \
  __builtin_amdgcn_global_load_lds(                                \
      (const __attribute__((address_space(1))) void*)(gp),         \
      (__attribute__((address_space(3))) void*)(lp), 16, 0, 2)
// MFMA 16x16x32 layouts (gfx950, per verified guide):
//  A: row = lane&15,           k = 8*(lane>>4)+j   (j=0..7)
//  B: col = lane&15,           k = 8*(lane>>4)+j
//  D: col = lane&15,           row = 4*(lane>>4)+r (r=0..3)

// ---------------------------------------------------------------------------
// Kernel 0: transpose 5 weight matrices [256][256] fp32 -> bf16 W^T [n][a]
// ---------------------------------------------------------------------------
__global__ __launch_bounds__(256) void wtrans_kernel(
    const float* __restrict__ qw, const float* __restrict__ kw,
    const float* __restrict__ vw, const float* __restrict__ gw,
    const float* __restrict__ ow,
    unsigned short* __restrict__ wtq, unsigned short* __restrict__ wtk,
    unsigned short* __restrict__ wtv, unsigned short* __restrict__ wtg,
    unsigned short* __restrict__ wt3)
{
  const int matid = blockIdx.x >> 4;
  const int tile  = blockIdx.x & 15;
  const float* src = (matid == 0) ? qw : (matid == 1) ? kw : (matid == 2) ? vw
                   : (matid == 3) ? gw : ow;
  unsigned short* dst = (matid == 0) ? wtq : (matid == 1) ? wtk : (matid == 2) ? wtv
                      : (matid == 3) ? wtg : wt3;
  const int tr = (tile >> 2) * 64, tc = (tile & 3) * 64;
  __shared__ unsigned short T[64 * 72];
  const int t = threadIdx.x;
  {
    const int row = t >> 2, cb = (t & 3) * 16;
#pragma unroll
    for (int ii = 0; ii < 4; ++ii) {
      f32x4 v = *(const f32x4*)&src[(size_t)(tr + row) * 256 + tc + cb + ii * 4];
      u32x2 p; p.x = pack2(v.x, v.y); p.y = pack2(v.z, v.w);
      *(u32x2*)&T[row * 72 + cb + ii * 4] = p;
    }
  }
  __syncthreads();
  {
    const int c0 = t >> 2, rb = (t & 3) * 16;
    unsigned short vals[16];
#pragma unroll
    for (int m = 0; m < 16; ++m) vals[m] = T[(rb + m) * 72 + c0];
    u32x4 s0, s1;
    s0.x = (unsigned)vals[0]  | ((unsigned)vals[1]  << 16);
    s0.y = (unsigned)vals[2]  | ((unsigned)vals[3]  << 16);
    s0.z = (unsigned)vals[4]  | ((unsigned)vals[5]  << 16);
    s0.w = (unsigned)vals[6]  | ((unsigned)vals[7]  << 16);
    s1.x = (unsigned)vals[8]  | ((unsigned)vals[9]  << 16);
    s1.y = (unsigned)vals[10] | ((unsigned)vals[11] << 16);
    s1.z = (unsigned)vals[12] | ((unsigned)vals[13] << 16);
    s1.w = (unsigned)vals[14] | ((unsigned)vals[15] << 16);
    unsigned short* dp = &dst[(size_t)(tc + c0) * 256 + tr + rb];
    *(u32x4*)dp = s0;
    *(u32x4*)(dp + 8) = s1;
  }
}

// ---------------------------------------------------------------------------
// Kernel 1: projections. blocks 0..255: q_data -> qp + gate.
//           blocks 256..511: m_data -> kp + vp.  All outputs [B,H,S,C].
// qp scaled by keyscale*log2e.
// ---------------------------------------------------------------------------
__global__ __launch_bounds__(512, 4) void proj_kernel(
    const float* __restrict__ q_data, const float* __restrict__ m_data,
    const unsigned short* __restrict__ wtq, const unsigned short* __restrict__ wtk,
    const unsigned short* __restrict__ wtv, const unsigned short* __restrict__ wtg,
    const float* __restrict__ gating_b,
    unsigned short* __restrict__ qp, unsigned short* __restrict__ kp,
    unsigned short* __restrict__ vp, unsigned short* __restrict__ gate)
{
  const int bid = blockIdx.x;
  const bool mside = bid >= 256;
  const int r0 = (mside ? bid - 256 : bid) * 64;
  const float* inp = mside ? m_data : q_data;
  __shared__ unsigned short Alds[64 * 264];       // 64 rows x 256 a, pad 264
  __shared__ unsigned short Wlds[2][256 * 40];    // dbuf: 256 n x 32 a-slice
  const int t = threadIdx.x;
  const int lane = t & 63, wave = t >> 6;
  const int l15 = lane & 15, g = lane >> 4;
  const int stripe = wave & 3, nhalf = wave >> 2;

  { // stage A tile as bf16: 512 threads x 32 floats
    const int row = t >> 3, cb = (t & 7) * 32;
    const float* ip = &inp[(size_t)(r0 + row) * 256 + cb];
#pragma unroll
    for (int i = 0; i < 4; ++i) {
      f32x4 a0 = *(const f32x4*)&ip[i * 8];
      f32x4 a1 = *(const f32x4*)&ip[i * 8 + 4];
      u32x4 pk;
      pk.x = pack2(a0.x, a0.y); pk.y = pack2(a0.z, a0.w);
      pk.z = pack2(a1.x, a1.y); pk.w = pack2(a1.z, a1.w);
      *(u32x4*)&Alds[row * 264 + cb + i * 8] = pk;
    }
  }

  const unsigned short* wt0 = mside ? wtk : wtq;
  const unsigned short* wt1 = mside ? wtv : wtg;
  const int wrow = t & 255, whalf = t >> 8;       // W staging: 2 threads/row

  { // prologue: W slice 0 -> buf 0
    const u32x4* wsrc = (const u32x4*)&wt0[(size_t)wrow * 256 + whalf * 16];
    u32x4 a = wsrc[0], b = wsrc[1];
    *(u32x4*)&Wlds[0][wrow * 40 + whalf * 16 + 0] = a;
    *(u32x4*)&Wlds[0][wrow * 40 + whalf * 16 + 8] = b;
  }

  f32x4 acc[8];
#pragma unroll
  for (int j = 0; j < 8; ++j) acc[j] = f32x4{0.f, 0.f, 0.f, 0.f};

  const int arow = (stripe * 16 + l15) * 264 + 8 * g;
  const int grow = r0 + stripe * 16 + l15;        // B-col -> data row (b*512+q)
  const int ob = grow >> 9, oq = grow & 511;

#pragma unroll
  for (int s = 0; s < 16; ++s) {                  // s = oi*8 + ks
    const int p = s & 1;
    __syncthreads();                               // buf p ready; buf p^1 free
    u32x4 nw0, nw1;
    if (s < 15) {                                  // issue next-slice W load
      const unsigned short* wt = (s + 1 < 8) ? wt0 : wt1;
      const u32x4* wsrc =
          (const u32x4*)&wt[(size_t)wrow * 256 + ((s + 1) & 7) * 32 + whalf * 16];
      nw0 = wsrc[0]; nw1 = wsrc[1];
    }
    const int ks = s & 7;
    short8 bf = __builtin_bit_cast(short8, *(const u32x4*)&Alds[arow + ks * 32]);
#pragma unroll
    for (int j = 0; j < 8; ++j) {
      short8 wf = __builtin_bit_cast(short8,
          *(const u32x4*)&Wlds[p][((nhalf * 8 + j) * 16 + l15) * 40 + 8 * g]);
      acc[j] = mfma16(wf, bf, acc[j]);             // D: row=n(4g+r), col=q(l15)
    }
    if (s < 15) {
      *(u32x4*)&Wlds[p ^ 1][wrow * 40 + whalf * 16 + 0] = nw0;
      *(u32x4*)&Wlds[p ^ 1][wrow * 40 + whalf * 16 + 8] = nw1;
    }
    if (s == 7 || s == 15) {                       // epilogue per oi
      const int oi = s >> 3;
      const float QS = 0.17677669529663687f * 1.4426950408889634f;
#pragma unroll
      for (int j = 0; j < 8; ++j) {
        const int n0 = (nhalf * 8 + j) * 16 + 4 * g;  // 4 consecutive n / lane
        const int h = n0 >> 5, c0 = n0 & 31;
        const size_t idx = ((size_t)(ob * 8 + h) * 512 + oq) * 32 + c0;
        f32x4 v = acc[j];
        if (!mside) {
          if (oi == 0) {
            u32x2 st;
            st.x = pack2(v.x * QS, v.y * QS);
            st.y = pack2(v.z * QS, v.w * QS);
            *(u32x2*)&qp[idx] = st;
          } else {
            f32x4 gb = *(const f32x4*)&gating_b[n0];
            f32x4 gv;
            gv.x = 1.0f / (1.0f + exp2f(-(v.x + gb.x) * L2E));
            gv.y = 1.0f / (1.0f + exp2f(-(v.y + gb.y) * L2E));
            gv.z = 1.0f / (1.0f + exp2f(-(v.z + gb.z) * L2E));
            gv.w = 1.0f / (1.0f + exp2f(-(v.w + gb.w) * L2E));
            u32x2 st;
            st.x = pack2(gv.x, gv.y); st.y = pack2(gv.z, gv.w);
            *(u32x2*)&gate[idx] = st;              // gate stored bf16
          }
        } else {
          u32x2 st;
          st.x = pack2(v.x, v.y); st.y = pack2(v.z, v.w);
          if (oi == 0) *(u32x2*)&kp[idx] = st;
          else         *(u32x2*)&vp[idx] = st;
        }
        acc[j] = f32x4{0.f, 0.f, 0.f, 0.f};
      }
    }
  }
}

// ---------------------------------------------------------------------------
// Kernel 2: fused attention. Grid 256 = (b,h); 1 block/CU; 8 waves.
// Two q-passes (256 rows each, wave owns 32 rows/pass) over ONE K/V staging.
// Token t = pass*16 + kt (32 tokens). bbias tile [256 q][32 k] fp32 dbuf'd,
// DMA'd 2 tokens ahead via global_load_lds (NT policy); per-token order:
//   [kt==0: qf loads] ds_read bias/K/V -> lgkmcnt(0)+sched_barrier
//   -> nbias prefetch (vm) -> DMA tile t+2 (vm)
//   -> setprio(1) compute setprio(0) -> vmcnt(8) [t==30: vmcnt(4)]
// vmcnt(8) leaves {nbias(t+1), DMA(t+2)} outstanding -> tile t+1 resident.
// Each wave DMAs only its own rows -> no in-loop barriers. Q loaded per-pass
// into NAMED regs qf0/qf1 (runtime-indexed arrays -> scratch, rule #20).
// ---------------------------------------------------------------------------
__global__ __launch_bounds__(512, 2) void attn_kernel(
    const unsigned short* __restrict__ qp, const unsigned short* __restrict__ kp,
    const unsigned short* __restrict__ vp,
    const float* __restrict__ bias, const float* __restrict__ nbias,
    const float* __restrict__ bbias,
    unsigned short* __restrict__ wa)
{
  const int bid = blockIdx.x;               // = b*8 + h
  const int h = bid & 7;                    // same-h blocks share an XCD -> nbias L2-hot
  const int b = bid >> 3;
  const int bh = bid;
  const int t = threadIdx.x;
  const int lane = t & 63, wave = t >> 6;
  const int l15 = lane & 15, g = lane >> 4;

  __shared__ unsigned short Klds[512 * 32];  // [k][c] unpadded (contiguous reads)
  __shared__ unsigned short Vt[32 * 520];    // V^T [c][k], pad 520 (2-way)
  __shared__ float Bb[2][8192];              // bbias tile dbuf: [256 q][32 k]
  __shared__ float Bk[512];                  // bias row * log2e

  // bbias DMA source. Chunk i (i=0..3) of this wave covers pass-local rows
  // wave*32 + i*8 + qc (qc = lane>>3); slot sl = lane&7 (16B units), source
  // column slot pre-swizzled: sl^qc (involution, matches read-side XOR).
  const float* bbb_bh = bbias + (size_t)bh * 262144;
  const int qc = lane >> 3, sl = lane & 7;
  const float* wsrc0 = bbb_bh + (size_t)(wave * 32 + qc) * 512 + ((sl ^ qc) << 2);

  // prologue: DMA tiles tok=0 (buf0) and tok=1 (buf1); drained by syncthreads
#pragma unroll
  for (int i = 0; i < 4; ++i)
    GLOAD_LDS16_NT(wsrc0 + i * 4096,      &Bb[0][(wave * 4 + i) * 256]);
#pragma unroll
  for (int i = 0; i < 4; ++i)
    GLOAD_LDS16_NT(wsrc0 + i * 4096 + 32, &Bb[1][(wave * 4 + i) * 256]);

  { // stage K rows + transposed V (512 threads, one k-row each)
    const int row = t;
    const u32x4* ks = (const u32x4*)&kp[((size_t)bh * 512 + row) * 32];
    u32x4 k0 = ks[0], k1 = ks[1], k2 = ks[2], k3 = ks[3];
    *(u32x4*)&Klds[row * 32 + 0]  = k0;
    *(u32x4*)&Klds[row * 32 + 8]  = k1;
    *(u32x4*)&Klds[row * 32 + 16] = k2;
    *(u32x4*)&Klds[row * 32 + 24] = k3;
    const u32x4* vs = (const u32x4*)&vp[((size_t)bh * 512 + row) * 32];
#pragma unroll
    for (int cc = 0; cc < 4; ++cc) {
      u32x4 vv = vs[cc];
      unsigned int dw0 = vv.x, dw1 = vv.y, dw2 = vv.z, dw3 = vv.w;
      const int c = cc * 8;
      Vt[(c + 0) * 520 + row] = (unsigned short)(dw0 & 0xffff);
      Vt[(c + 1) * 520 + row] = (unsigned short)(dw0 >> 16);
      Vt[(c + 2) * 520 + row] = (unsigned short)(dw1 & 0xffff);
      Vt[(c + 3) * 520 + row] = (unsigned short)(dw1 >> 16);
      Vt[(c + 4) * 520 + row] = (unsigned short)(dw2 & 0xffff);
      Vt[(c + 5) * 520 + row] = (unsigned short)(dw2 >> 16);
      Vt[(c + 6) * 520 + row] = (unsigned short)(dw3 & 0xffff);
      Vt[(c + 7) * 520 + row] = (unsigned short)(dw3 >> 16);
    }
    if (t < 128) {                           // stage bias row, pre-scaled
      f32x4 bv = *(const f32x4*)&bias[(size_t)b * 512 + t * 4];
      bv.x *= L2E; bv.y *= L2E; bv.z *= L2E; bv.w *= L2E;
      *(f32x4*)&Bk[t * 4] = bv;
    }
  }

  const int pib = ((g & 1) << 4) | ((g >> 1) << 3);  // pi = [0,16,8,24]
  const bool godd = (g & 1) != 0;
  const int sw0 = (g ^ (l15 & 7)) << 2;              // swizzled col slot (floats)
  const int sw1 = ((g + 4) ^ (l15 & 7)) << 2;
  const int bq0 = (wave * 32 + l15) * 32;            // qt0 row base in tile
  const int bq1 = bq0 + 16 * 32;                     // qt1 rows

  // nbias Cn for token 0
  f32x4 Cn00, Cn01, Cn10, Cn11;
  {
    const float* nn = nbias + (size_t)h * 262144
                    + (size_t)(wave * 32 + l15) * 512 + 4 * g;
    Cn00 = *(const f32x4*)nn;
    Cn01 = *(const f32x4*)(nn + 16);
    Cn10 = *(const f32x4*)(nn + 16 * 512);
    Cn11 = *(const f32x4*)(nn + 16 * 512 + 16);
  }

  short8 qf0, qf1;
  f32x4 acc[2][2];
  float l_part[2] = {0.f, 0.f};

  __syncthreads();   // K/V/Bk visible; prologue DMA drained (tiles 0,1 ready)

  for (int tok = 0; tok < 32; ++tok) {
    const int pass = tok >> 4, kt = tok & 15, p = tok & 1;
    const int k0 = kt * 32;

    if (kt == 0) {   // pass start: load Q fragments (named regs), reset acc
      const int qbase = pass * 256 + wave * 32;
      qf0 = __builtin_bit_cast(short8,
          *(const u32x4*)&qp[((size_t)bh * 512 + qbase + l15) * 32 + 8 * g]);
      qf1 = __builtin_bit_cast(short8,
          *(const u32x4*)&qp[((size_t)bh * 512 + qbase + 16 + l15) * 32 + 8 * g]);
#pragma unroll
      for (int ct = 0; ct < 2; ++ct)
#pragma unroll
        for (int qt = 0; qt < 2; ++qt) acc[ct][qt] = f32x4{0.f, 0.f, 0.f, 0.f};
      l_part[0] = 0.f; l_part[1] = 0.f;
    }

    // LDS reads for this token
    short8 kf0 = __builtin_bit_cast(short8, *(const u32x4*)&Klds[(k0 + l15) * 32 + 8 * g]);
    short8 kf1 = __builtin_bit_cast(short8, *(const u32x4*)&Klds[(k0 + 16 + l15) * 32 + 8 * g]);
    short8 vf0 = __builtin_bit_cast(short8, *(const u32x4*)&Vt[l15 * 520 + k0 + pib]);
    short8 vf1 = __builtin_bit_cast(short8, *(const u32x4*)&Vt[(16 + l15) * 520 + k0 + pib]);
    f32x4 bks0 = *(const f32x4*)&Bk[k0 + 4 * g];
    f32x4 bks1 = *(const f32x4*)&Bk[k0 + 16 + 4 * g];
    const float* bp = Bb[p];
    f32x4 bb00 = *(const f32x4*)&bp[bq0 + sw0];
    f32x4 bb01 = *(const f32x4*)&bp[bq0 + sw1];
    f32x4 bb10 = *(const f32x4*)&bp[bq1 + sw0];
    f32x4 bb11 = *(const f32x4*)&bp[bq1 + sw1];
    // bias regs must be materialized before the same-buffer DMA below
    asm volatile("s_waitcnt lgkmcnt(0)" ::: "memory");
    __builtin_amdgcn_sched_barrier(0);

    // nbias prefetch for tok+1 (issued BEFORE the tile DMA: its implicit
    // wait at next token's compute must not drain the tile pipeline)
    f32x4 Nn00, Nn01, Nn10, Nn11;
    if (tok < 31) {
      const int nt = tok + 1;
      const float* nn = nbias + (size_t)h * 262144
          + (size_t)((nt >> 4) * 256 + wave * 32 + l15) * 512 + (nt & 15) * 32 + 4 * g;
      Nn00 = *(const f32x4*)nn;
      Nn01 = *(const f32x4*)(nn + 16);
      Nn10 = *(const f32x4*)(nn + 16 * 512);
      Nn11 = *(const f32x4*)(nn + 16 * 512 + 16);
    }

    // DMA tile tok+2 into buf p (this wave's rows were just read to regs)
    if (tok < 30) {
      const int ft = tok + 2;
      const float* ws = wsrc0 + (size_t)(ft >> 4) * 131072 + (ft & 15) * 32;
#pragma unroll
      for (int i = 0; i < 4; ++i)
        GLOAD_LDS16_NT(ws + (size_t)i * 4096, &Bb[p][(wave * 4 + i) * 256]);
    }

    // compute both q-tiles (prioritized: waves are phase-independent here,
    // so the CU scheduler can favor compute-phase waves -- T5/m191)
    __builtin_amdgcn_s_setprio(1);
#pragma unroll
    for (int qt = 0; qt < 2; ++qt) {
      f32x4 bb0 = qt ? bb10 : bb00;
      f32x4 bb1 = qt ? bb11 : bb01;
      f32x4 nb0 = qt ? Cn10 : Cn00;
      f32x4 nb1 = qt ? Cn11 : Cn01;
      f32x4 c0 = bb0 * L2E + (nb0 * L2E + bks0);
      f32x4 c1 = bb1 * L2E + (nb1 * L2E + bks1);
      short8 qf = qt ? qf1 : qf0;
      f32x4 s0 = mfma16(kf0, qf, c0);        // S^T: row k=4g+r, col q=l15
      f32x4 s1 = mfma16(kf1, qf, c1);
      f32x4 p0, p1;                          // logits carry log2e -> exp2
      p0.x = exp2f(s0.x); p0.y = exp2f(s0.y);
      p0.z = exp2f(s0.z); p0.w = exp2f(s0.w);
      p1.x = exp2f(s1.x); p1.y = exp2f(s1.y);
      p1.z = exp2f(s1.z); p1.w = exp2f(s1.w);
      l_part[qt] += ((p0.x + p0.y) + (p0.z + p0.w)) +
                    ((p1.x + p1.y) + (p1.z + p1.w));
      // assemble P^T B-fragment (col q=l15, k-slots permuted by pi)
      unsigned int d0 = pack2(p0.x, p0.y), d1 = pack2(p0.z, p0.w);
      unsigned int e0 = pack2(p1.x, p1.y), e1 = pack2(p1.z, p1.w);
      unsigned int pd0 = __shfl_xor(d0, 16, 64), pd1 = __shfl_xor(d1, 16, 64);
      unsigned int pe0 = __shfl_xor(e0, 16, 64), pe1 = __shfl_xor(e1, 16, 64);
      u32x4 pfu;
      pfu.x = godd ? pe0 : d0;
      pfu.y = godd ? pe1 : d1;
      pfu.z = godd ? e0 : pd0;
      pfu.w = godd ? e1 : pd1;
      short8 pf = __builtin_bit_cast(short8, pfu);
      acc[0][qt] = mfma16(vf0, pf, acc[0][qt]);   // wa^T: row c, col q
      acc[1][qt] = mfma16(vf1, pf, acc[1][qt]);
    }
    __builtin_amdgcn_s_setprio(0);

    if (tok < 31) { Cn00 = Nn00; Cn01 = Nn01; Cn10 = Nn10; Cn11 = Nn11; }

    // counted wait: leaves {nbias(t+1), DMA(t+2)} in flight; tile t+1 resident
    if (tok < 30)       asm volatile("s_waitcnt vmcnt(8)" ::: "memory");
    else if (tok == 30) asm volatile("s_waitcnt vmcnt(4)" ::: "memory");

    if (kt == 15) {     // pass epilogue (after the wait: stores stay youngest)
      const int qbase = pass * 256 + wave * 32;
      unsigned short* wab = wa + (size_t)bh * 512 * 32;
#pragma unroll
      for (int qt = 0; qt < 2; ++qt) {
        float l = l_part[qt];
        l += __shfl_xor(l, 16, 64);
        l += __shfl_xor(l, 32, 64);
        const float rl = 1.0f / l;
        const int q = qbase + qt * 16 + l15;
#pragma unroll
        for (int ct = 0; ct < 2; ++ct) {
          f32x4 v = acc[ct][qt];
          u32x2 st;
          st.x = pack2(v.x * rl, v.y * rl);
          st.y = pack2(v.z * rl, v.w * rl);
          *(u32x2*)&wab[q * 32 + ct * 16 + 4 * g] = st;
        }
      }
    }
  }
}

// ---------------------------------------------------------------------------
// Kernel 3: out[b,q,o] = sum_hc wa*gate * W3[hc][o] + output_b[o]
// 32 rows/block (grid 512 -> 2 blocks/CU), n-split across wave pairs;
// gate read bf16; W3 dbuf; act prefetched; cvt_pk packs.
// ---------------------------------------------------------------------------
__global__ __launch_bounds__(256, 2) void outp_kernel(
    const unsigned short* __restrict__ wa, const unsigned short* __restrict__ gate,
    const unsigned short* __restrict__ wt3, const float* __restrict__ out_b,
    float* __restrict__ out)
{
  const int r0 = blockIdx.x * 32;
  const int t = threadIdx.x;
  const int lane = t & 63, wave = t >> 6;
  const int l15 = lane & 15, g = lane >> 4;
  const int stripe = wave & 1, half = wave >> 1;
  __shared__ unsigned short Wlds[2][256 * 40];

  const int grow = r0 + stripe * 16 + l15;   // B-col -> data row (b*512+q)
  const int b = grow >> 9, q = grow & 511;

  { // prologue: W3 slice 0 -> buf 0 (256 threads, one n-row each)
    const u32x4* wsrc = (const u32x4*)&wt3[(size_t)t * 256];
    u32x4 a = wsrc[0], bb = wsrc[1], c = wsrc[2], d = wsrc[3];
    *(u32x4*)&Wlds[0][t * 40 + 0]  = a;
    *(u32x4*)&Wlds[0][t * 40 + 8]  = bb;
    *(u32x4*)&Wlds[0][t * 40 + 16] = c;
    *(u32x4*)&Wlds[0][t * 40 + 24] = d;
  }
  // prologue: activation slice 0 (h = 0)
  size_t aidx = ((size_t)(b * 8 + 0) * 512 + q) * 32 + 8 * g;
  u32x4 cwv = *(const u32x4*)&wa[aidx];
  u32x4 cgv = *(const u32x4*)&gate[aidx];

  f32x4 acc[8];
#pragma unroll
  for (int j = 0; j < 8; ++j) acc[j] = f32x4{0.f, 0.f, 0.f, 0.f};

#pragma unroll
  for (int s = 0; s < 8; ++s) {              // slice s: h = s, c = 8g..8g+7
    const int p = s & 1;
    __syncthreads();
    u32x4 nw0, nw1, nw2, nw3, nwv, ngv;
    if (s < 7) {
      const u32x4* wsrc = (const u32x4*)&wt3[(size_t)t * 256 + (s + 1) * 32];
      nw0 = wsrc[0]; nw1 = wsrc[1]; nw2 = wsrc[2]; nw3 = wsrc[3];
      const size_t na = ((size_t)(b * 8 + s + 1) * 512 + q) * 32 + 8 * g;
      nwv = *(const u32x4*)&wa[na];
      ngv = *(const u32x4*)&gate[na];
    }
    // build gated-activation B-fragment from current regs (both bf16)
    float f0 = b2f(cwv.x & 0xffff) * b2f(cgv.x & 0xffff);
    float f1 = b2f(cwv.x >> 16)    * b2f(cgv.x >> 16);
    float f2 = b2f(cwv.y & 0xffff) * b2f(cgv.y & 0xffff);
    float f3 = b2f(cwv.y >> 16)    * b2f(cgv.y >> 16);
    float f4 = b2f(cwv.z & 0xffff) * b2f(cgv.z & 0xffff);
    float f5 = b2f(cwv.z >> 16)    * b2f(cgv.z >> 16);
    float f6 = b2f(cwv.w & 0xffff) * b2f(cgv.w & 0xffff);
    float f7 = b2f(cwv.w >> 16)    * b2f(cgv.w >> 16);
    u32x4 au;
    au.x = pack2(f0, f1); au.y = pack2(f2, f3);
    au.z = pack2(f4, f5); au.w = pack2(f6, f7);
    short8 af = __builtin_bit_cast(short8, au);
#pragma unroll
    for (int j = 0; j < 8; ++j) {
      short8 wf = __builtin_bit_cast(short8,
          *(const u32x4*)&Wlds[p][((half * 8 + j) * 16 + l15) * 40 + 8 * g]);
      acc[j] = mfma16(wf, af, acc[j]);       // D: row=o(4g+r), col=q(l15)
    }
    if (s < 7) {
      *(u32x4*)&Wlds[p ^ 1][t * 40 + 0]  = nw0;
      *(u32x4*)&Wlds[p ^ 1][t * 40 + 8]  = nw1;
      *(u32x4*)&Wlds[p ^ 1][t * 40 + 16] = nw2;
      *(u32x4*)&Wlds[p ^ 1][t * 40 + 24] = nw3;
      cwv = nwv; cgv = ngv;
    }
  }
#pragma unroll
  for (int j = 0; j < 8; ++j) {
    const int o0 = (half * 8 + j) * 16 + 4 * g;  // 4 consecutive o per lane
    f32x4 ob4 = *(const f32x4*)&out_b[o0];
    f32x4 v = acc[j] + ob4;
    *(f32x4*)&out[(size_t)grow * 256 + o0] = v;
  }
}

// ---------------------------------------------------------------------------
extern "C" void kernel_launch(void* const* d_in, const int* in_sizes, int n_in,
                              void* d_out, int out_size, void* d_ws, size_t ws_size,
                              hipStream_t stream)
{
  const float* q_data   = (const float*)d_in[0];
  const float* m_data   = (const float*)d_in[1];
  const float* bias     = (const float*)d_in[2];
  const float* nbb      = (const float*)d_in[3];
  const float* bbb      = (const float*)d_in[4];
  const float* query_w  = (const float*)d_in[5];
  const float* key_w    = (const float*)d_in[6];
  const float* value_w  = (const float*)d_in[7];
  const float* gating_w = (const float*)d_in[8];
  const float* gating_b = (const float*)d_in[9];
  const float* output_w = (const float*)d_in[10];
  const float* output_b = (const float*)d_in[11];
  float* out = (float*)d_out;

  const size_t QP_B   = (size_t)32 * 8 * 512 * 32 * 2;  // 8 MiB bf16 [B,H,S,C]
  const size_t GATE_B = (size_t)32 * 8 * 512 * 32 * 2;  // 8 MiB bf16
  const size_t WT_B   = (size_t)256 * 256 * 2;

  char* ws = (char*)d_ws;
  unsigned short* qp  = (unsigned short*)(ws);
  unsigned short* kp  = (unsigned short*)(ws + QP_B);
  unsigned short* vp  = (unsigned short*)(ws + 2 * QP_B);
  unsigned short* wab = (unsigned short*)(ws + 3 * QP_B);
  unsigned short* gat = (unsigned short*)(ws + 4 * QP_B);
  unsigned short* wtq = (unsigned short*)(ws + 4 * QP_B + GATE_B);
  unsigned short* wtk = (unsigned short*)(ws + 4 * QP_B + GATE_B + WT_B);
  unsigned short* wtv = (unsigned short*)(ws + 4 * QP_B + GATE_B + 2 * WT_B);
  unsigned short* wtg = (unsigned short*)(ws + 4 * QP_B + GATE_B + 3 * WT_B);
  unsigned short* wt3 = (unsigned short*)(ws + 4 * QP_B + GATE_B + 4 * WT_B);
  const size_t need = 4 * QP_B + GATE_B + 5 * WT_B;
  if (ws_size < need) return;  // fail loudly (out stays poisoned)

  hipLaunchKernelGGL(wtrans_kernel, dim3(80), dim3(256), 0, stream,
                     query_w, key_w, value_w, gating_w, output_w,
                     wtq, wtk, wtv, wtg, wt3);
  hipLaunchKernelGGL(proj_kernel, dim3(512), dim3(512), 0, stream,
                     q_data, m_data, wtq, wtk, wtv, wtg, gating_b,
                     qp, kp, vp, gat);
  hipLaunchKernelGGL(attn_kernel, dim3(256), dim3(512), 0, stream,
                     qp, kp, vp, bias, nbb, bbb, wab);
  hipLaunchKernelGGL(outp_kernel, dim3(512), dim3(256), 0, stream,
                     wab, gat, wt3, output_b, out);
}